// Round 4
// baseline (267.769 us; speedup 1.0000x reference)
//
#include <hip/hip_runtime.h>

#define N_TOK 131072
#define TILE 128             // tokens per block (16 per wave x 8 waves)
#define NT_MAX 1040          // N_TOK/TILE + 16 tasks worth of padding tiles
#define HS 264               // H row stride (bf16 elems): 256 + 8 pad
#define SLOT 8448            // per-wave LDS slot (elems): H1 4224 + H2 4224

typedef __attribute__((ext_vector_type(8))) short s8v;
typedef __attribute__((ext_vector_type(4))) short s4v;
typedef __attribute__((ext_vector_type(4))) float f4v;
typedef unsigned short ushort_t;

__device__ __forceinline__ unsigned short f2bf(float x) {
    union { float f; unsigned u; } v; v.f = x;
    unsigned r = v.u + 0x7fffu + ((v.u >> 16) & 1u);   // RNE
    return (unsigned short)(r >> 16);
}

__device__ __forceinline__ float tanh_fast(float x) {
    float e = __expf(2.0f * x);
    return 1.0f - 2.0f / (e + 1.0f);
}

// ------------------------------------------------- fused prep + hist
// blocks [0,224): repack weights to bf16 MFMA fragments (one 16B write/thread).
// Fragment r = (ftile*(K>>5)+kt)*64 + lane; elem j holds W[k][n] with
// n = ftile*16 + (lane&15), k = kt*32 + (lane>>4)*8 + j.  (A operand of
// Y^T = W^T X^T: A[m=lane&15][k=(lane>>4)*8+j] = W^T[m][k].)
// blocks [224,288): 16-bin histogram of task[], 2048 tokens/block.
__global__ void prep_hist_kernel(const float* __restrict__ W0, const float* __restrict__ W1,
                                 const float* __restrict__ W2,
                                 ushort_t* __restrict__ W0p, ushort_t* __restrict__ W1p,
                                 ushort_t* __restrict__ W2p,
                                 const int* __restrict__ task, int* __restrict__ blockCounts) {
    if (blockIdx.x < 224) {
        int f = blockIdx.x * 256 + threadIdx.x;   // 57344 total fragments
        const float* src; ushort_t* dst; int K, N;
        if (f < 16384)      { src = W0; dst = W0p; K = 128; N = 256; }
        else if (f < 49152) { src = W1; dst = W1p; K = 256; N = 256; f -= 16384; }
        else                { src = W2; dst = W2p; K = 256; N = 64;  f -= 49152; }
        int fpc = (N >> 4) * (K >> 5) * 64;       // fragments per copy
        int c = f / fpc, r = f % fpc;
        int lane = r & 63;
        int kt = (r >> 6) % (K >> 5);
        int ftile = (r >> 6) / (K >> 5);
        int n = ftile * 16 + (lane & 15);
        int kbase = kt * 32 + (lane >> 4) * 8;
        const float* s = src + (size_t)c * K * N + (size_t)kbase * N + n;
        s8v pk;
#pragma unroll
        for (int j = 0; j < 8; j++) pk[j] = (short)f2bf(s[(size_t)j * N]);
        *reinterpret_cast<s8v*>(dst + ((size_t)(c * fpc + r) << 3)) = pk;
    } else {
        __shared__ int cnt[16];
        int t = threadIdx.x;
        int hb = blockIdx.x - 224;
        if (t < 16) cnt[t] = 0;
        __syncthreads();
        int base = hb * 2048 + t;
#pragma unroll
        for (int i = 0; i < 8; i++) atomicAdd(&cnt[task[base + i * 256]], 1);
        __syncthreads();
        if (t < 16) blockCounts[hb * 16 + t] = cnt[t];
    }
}

// ------------------------------------------------- fused scan + scatter
// 64 blocks. Each block redundantly reads all 64x16 counts, computes global
// 128-aligned bases + its own prefix, then scatters its 2048 tokens.
__global__ void sort_kernel(const int* __restrict__ task, const int* __restrict__ blockCounts,
                            int* __restrict__ tileTask, int* __restrict__ nT,
                            int* __restrict__ perm) {
    __shared__ int cntLds[1024];
    __shared__ int total[16], pref[16], rank[16];
    __shared__ int tokBase[16], tbase[17];
    int t = threadIdx.x, b = blockIdx.x;
    for (int i = t; i < 1024; i += 256) cntLds[i] = blockCounts[i];
    if (t < 16) rank[t] = 0;
    __syncthreads();
    if (t < 16) {
        int tot = 0, pf = 0;
#pragma unroll
        for (int bb = 0; bb < 64; bb++) {
            int v = cntLds[bb * 16 + t];
            tot += v;
            if (bb < b) pf += v;
        }
        total[t] = tot; pref[t] = pf;
    }
    __syncthreads();
    if (t == 0) {
        int tok = 0, tile = 0;
        for (int k = 0; k < 16; k++) {
            tokBase[k] = tok;
            tbase[k] = tile;
            int ntk = (total[k] + TILE - 1) / TILE;
            tok += ntk * TILE;
            tile += ntk;
        }
        tbase[16] = tile;
        if (b == 0) nT[0] = tile;
    }
    __syncthreads();
    if (b == 0) {
        for (int i = t; i < NT_MAX; i += 256) {
            int tk = 0;
            if (i < tbase[16]) {
#pragma unroll
                for (int k = 0; k < 16; k++) if (i >= tbase[k]) tk = k;
            }
            tileTask[i] = tk;
        }
    }
    int tk[8], my[8];
#pragma unroll
    for (int i = 0; i < 8; i++) {
        int idx = b * 2048 + i * 256 + t;
        tk[i] = task[idx];
        my[i] = atomicAdd(&rank[tk[i]], 1);
    }
#pragma unroll
    for (int i = 0; i < 8; i++) {
        int idx = b * 2048 + i * 256 + t;
        perm[tokBase[tk[i]] + pref[tk[i]] + my[i]] = idx;
    }
}

// ------------------------------------------------- wave-private fused MLP
// Wave w owns tokens [b*128 + w*16, +16): computes ALL 256 features itself
// (acc[16] tiles). Activations never cross waves: X B-frags come straight
// from global; H1/H2 live in a private LDS slot. Barriers are only for
// phase-aligning waves so per-kt weight slices (16KB) dedupe in L1.
__launch_bounds__(512, 2)
__global__ void mlp_kernel(const float* __restrict__ x_in,
                           const int* __restrict__ cmap,
                           const float* __restrict__ b0,
                           const float* __restrict__ b1,
                           const float* __restrict__ b2,
                           const ushort_t* __restrict__ W0p,
                           const ushort_t* __restrict__ W1p,
                           const ushort_t* __restrict__ W2p,
                           const int* __restrict__ tileTask,
                           const int* __restrict__ nTp,
                           const int* __restrict__ perm,
                           float* __restrict__ out) {
    __shared__ __align__(16) ushort_t lds[8 * SLOT];   // 135168 B

    int b = blockIdx.x;
    if (b >= nTp[0]) return;
    int t = threadIdx.x;
    int task = tileTask[b];
    int c0 = cmap[task], c1 = cmap[16 + task], c2 = cmap[32 + task];

    int w = t >> 6;                 // wave 0..7
    int lane = t & 63;
    int l15 = lane & 15, lq = lane >> 4;

    ushort_t* H1 = &lds[w * SLOT];
    ushort_t* H2 = H1 + 4224;

    int tok = perm[b * TILE + w * 16 + l15];   // same across lq
    bool valid = (unsigned)tok < (unsigned)N_TOK;

    // ---- Layer 0: H1^T = W0^T X^T.  X B-frags direct from global.
    {
        f4v acc[16];
#pragma unroll
        for (int mt = 0; mt < 16; mt++) { f4v z = {0.f, 0.f, 0.f, 0.f}; acc[mt] = z; }
        const ushort_t* Wc = W0p + (size_t)c0 * 32768;
#pragma unroll
        for (int kt = 0; kt < 4; kt++) {
            float4 u0 = make_float4(0.f, 0.f, 0.f, 0.f), u1 = u0;
            if (valid) {
                const float4* src = reinterpret_cast<const float4*>(x_in + (size_t)tok * 128 + kt * 32 + lq * 8);
                u0 = src[0]; u1 = src[1];
            }
            s8v xb;
            xb[0] = (short)f2bf(u0.x); xb[1] = (short)f2bf(u0.y);
            xb[2] = (short)f2bf(u0.z); xb[3] = (short)f2bf(u0.w);
            xb[4] = (short)f2bf(u1.x); xb[5] = (short)f2bf(u1.y);
            xb[6] = (short)f2bf(u1.z); xb[7] = (short)f2bf(u1.w);
#pragma unroll
            for (int mt = 0; mt < 16; mt++) {
                s8v wa = *reinterpret_cast<const s8v*>(Wc + (((mt * 4 + kt) * 64 + lane) << 3));
                acc[mt] = __builtin_amdgcn_mfma_f32_16x16x32_bf16(wa, xb, acc[mt], 0, 0, 0);
            }
        }
#pragma unroll
        for (int mt = 0; mt < 16; mt++) {
            float4 bv = *reinterpret_cast<const float4*>(b0 + c0 * 256 + mt * 16 + lq * 4);
            s4v pk;
            pk[0] = (short)f2bf(tanh_fast(acc[mt][0] + bv.x));
            pk[1] = (short)f2bf(tanh_fast(acc[mt][1] + bv.y));
            pk[2] = (short)f2bf(tanh_fast(acc[mt][2] + bv.z));
            pk[3] = (short)f2bf(tanh_fast(acc[mt][3] + bv.w));
            *reinterpret_cast<s4v*>(&H1[l15 * HS + mt * 16 + lq * 4]) = pk;
        }
    }
    __syncthreads();   // phase alignment only (no cross-wave data)

    // ---- Layer 1: H2^T = W1^T H1^T.
    {
        f4v acc[16];
#pragma unroll
        for (int mt = 0; mt < 16; mt++) { f4v z = {0.f, 0.f, 0.f, 0.f}; acc[mt] = z; }
        const ushort_t* Wc = W1p + (size_t)c1 * 65536;
#pragma unroll
        for (int kt = 0; kt < 8; kt++) {
            s8v xb = *reinterpret_cast<const s8v*>(&H1[l15 * HS + kt * 32 + lq * 8]);
#pragma unroll
            for (int mt = 0; mt < 16; mt++) {
                s8v wa = *reinterpret_cast<const s8v*>(Wc + (((mt * 8 + kt) * 64 + lane) << 3));
                acc[mt] = __builtin_amdgcn_mfma_f32_16x16x32_bf16(wa, xb, acc[mt], 0, 0, 0);
            }
        }
#pragma unroll
        for (int mt = 0; mt < 16; mt++) {
            float4 bv = *reinterpret_cast<const float4*>(b1 + c1 * 256 + mt * 16 + lq * 4);
            s4v pk;
            pk[0] = (short)f2bf(tanh_fast(acc[mt][0] + bv.x));
            pk[1] = (short)f2bf(tanh_fast(acc[mt][1] + bv.y));
            pk[2] = (short)f2bf(tanh_fast(acc[mt][2] + bv.z));
            pk[3] = (short)f2bf(tanh_fast(acc[mt][3] + bv.w));
            *reinterpret_cast<s4v*>(&H2[l15 * HS + mt * 16 + lq * 4]) = pk;
        }
    }
    __syncthreads();   // phase alignment only

    // ---- Layer 2: O^T = W2^T H2^T -> global (float4 per mt).
    {
        f4v acc[4];
#pragma unroll
        for (int mt = 0; mt < 4; mt++) { f4v z = {0.f, 0.f, 0.f, 0.f}; acc[mt] = z; }
        const ushort_t* Wc = W2p + (size_t)c2 * 16384;
#pragma unroll
        for (int kt = 0; kt < 8; kt++) {
            s8v xb = *reinterpret_cast<const s8v*>(&H2[l15 * HS + kt * 32 + lq * 8]);
#pragma unroll
            for (int mt = 0; mt < 4; mt++) {
                s8v wa = *reinterpret_cast<const s8v*>(Wc + (((mt * 8 + kt) * 64 + lane) << 3));
                acc[mt] = __builtin_amdgcn_mfma_f32_16x16x32_bf16(wa, xb, acc[mt], 0, 0, 0);
            }
        }
        if (valid) {
#pragma unroll
            for (int mt = 0; mt < 4; mt++) {
                float4 bv = *reinterpret_cast<const float4*>(b2 + c2 * 64 + mt * 16 + lq * 4);
                float4 o;
                o.x = acc[mt][0] + bv.x; o.y = acc[mt][1] + bv.y;
                o.z = acc[mt][2] + bv.z; o.w = acc[mt][3] + bv.w;
                *reinterpret_cast<float4*>(out + (size_t)tok * 64 + mt * 16 + lq * 4) = o;
            }
        }
    }
}

// ---------------------------------------------------------------- launch
extern "C" void kernel_launch(void* const* d_in, const int* in_sizes, int n_in,
                              void* d_out, int out_size, void* d_ws, size_t ws_size,
                              hipStream_t stream) {
    const float* inputs = (const float*)d_in[0];
    const int*   task   = (const int*)d_in[1];
    const int*   cmap   = (const int*)d_in[2];
    const float* W0     = (const float*)d_in[3];
    const float* b0     = (const float*)d_in[4];
    const float* W1     = (const float*)d_in[5];
    const float* b1     = (const float*)d_in[6];
    const float* W2     = (const float*)d_in[7];
    const float* b2     = (const float*)d_in[8];
    float* out = (float*)d_out;

    char* ws = (char*)d_ws;
    int* blockCounts = (int*)(ws + 0);            // 64*16*4 = 4096 B
    int* nT          = (int*)(ws + 4096);         // 4 B
    int* tileTask    = (int*)(ws + 4160);         // 1040*4 = 4160 B
    int* perm        = (int*)(ws + 8320);         // 1040*128*4 = 532480 B
    ushort_t* W0p    = (ushort_t*)(ws + 540800);  // 262144 B
    ushort_t* W1p    = (ushort_t*)(ws + 802944);  // 524288 B
    ushort_t* W2p    = (ushort_t*)(ws + 1327232); // 131072 B -> total ~1.46 MB

    prep_hist_kernel<<<288, 256, 0, stream>>>(W0, W1, W2, W0p, W1p, W2p, task, blockCounts);
    sort_kernel<<<64, 256, 0, stream>>>(task, blockCounts, tileTask, nT, perm);
    mlp_kernel<<<NT_MAX, 512, 0, stream>>>(inputs, cmap, b0, b1, b2,
                                           W0p, W1p, W2p, tileTask, nT, perm, out);
}

// Round 5
// 175.322 us; speedup vs baseline: 1.5273x; 1.5273x over previous
//
#include <hip/hip_runtime.h>

#define N_TOK 131072
#define TILE 32              // tokens per block
#define NT_MAX 4112          // N_TOK/TILE + 16 tasks worth of padding tiles

typedef __attribute__((ext_vector_type(8))) short s8v;
typedef __attribute__((ext_vector_type(4))) float f4v;
typedef unsigned short ushort_t;

__device__ __forceinline__ unsigned short f2bf(float x) {
    union { float f; unsigned u; } v; v.f = x;
    unsigned r = v.u + 0x7fffu + ((v.u >> 16) & 1u);   // RNE (prep only)
    return (unsigned short)(r >> 16);
}

// round-half-up pack of two f32 -> packed bf16x2 (1 ulp vs RNE only at ties)
__device__ __forceinline__ unsigned pk2(float a, float b) {
    union { float f; unsigned u; } x, y; x.f = a; y.f = b;
    return ((x.u + 0x8000u) >> 16) | ((y.u + 0x8000u) & 0xffff0000u);
}

__device__ __forceinline__ float tanh_fast(float x) {
    float e = __expf(2.0f * x);
    return 1.0f - 2.0f / (e + 1.0f);
}

// ------------------------------------------------- fused prep + hist
// blocks [0,224): repack weights to bf16 MFMA fragments (one 16B write/thread).
// Fragment r = (ftile*(K>>5)+kt)*64 + lane; elem j holds W[k][n] with
// n = ftile*16 + (lane&15), k = kt*32 + (lane>>4)*8 + j.  (A operand of
// Y^T = W^T X^T.)   blocks [224,288): 16-bin histogram of task[].
__global__ void prep_hist_kernel(const float* __restrict__ W0, const float* __restrict__ W1,
                                 const float* __restrict__ W2,
                                 ushort_t* __restrict__ W0p, ushort_t* __restrict__ W1p,
                                 ushort_t* __restrict__ W2p,
                                 const int* __restrict__ task, int* __restrict__ blockCounts) {
    if (blockIdx.x < 224) {
        int f = blockIdx.x * 256 + threadIdx.x;   // 57344 total fragments
        const float* src; ushort_t* dst; int K, N;
        if (f < 16384)      { src = W0; dst = W0p; K = 128; N = 256; }
        else if (f < 49152) { src = W1; dst = W1p; K = 256; N = 256; f -= 16384; }
        else                { src = W2; dst = W2p; K = 256; N = 64;  f -= 49152; }
        int fpc = (N >> 4) * (K >> 5) * 64;       // fragments per copy
        int c = f / fpc, r = f % fpc;
        int lane = r & 63;
        int kt = (r >> 6) % (K >> 5);
        int ftile = (r >> 6) / (K >> 5);
        int n = ftile * 16 + (lane & 15);
        int kbase = kt * 32 + (lane >> 4) * 8;
        const float* s = src + (size_t)c * K * N + (size_t)kbase * N + n;
        s8v pk;
#pragma unroll
        for (int j = 0; j < 8; j++) pk[j] = (short)f2bf(s[(size_t)j * N]);
        *reinterpret_cast<s8v*>(dst + ((size_t)(c * fpc + r) << 3)) = pk;
    } else {
        __shared__ int cnt[16];
        int t = threadIdx.x;
        int hb = blockIdx.x - 224;
        if (t < 16) cnt[t] = 0;
        __syncthreads();
        int base = hb * 2048 + t;
#pragma unroll
        for (int i = 0; i < 8; i++) atomicAdd(&cnt[task[base + i * 256]], 1);
        __syncthreads();
        if (t < 16) blockCounts[hb * 16 + t] = cnt[t];
    }
}

// ------------------------------------------------- fused scan + scatter
__global__ void sort_kernel(const int* __restrict__ task, const int* __restrict__ blockCounts,
                            int* __restrict__ tileTask, int* __restrict__ nT,
                            int* __restrict__ perm) {
    __shared__ int cntLds[1024];
    __shared__ int total[16], pref[16], rank[16];
    __shared__ int tokBase[16], tbase[17];
    int t = threadIdx.x, b = blockIdx.x;
    for (int i = t; i < 1024; i += 256) cntLds[i] = blockCounts[i];
    if (t < 16) rank[t] = 0;
    __syncthreads();
    if (t < 16) {
        int tot = 0, pf = 0;
#pragma unroll
        for (int bb = 0; bb < 64; bb++) {
            int v = cntLds[bb * 16 + t];
            tot += v;
            if (bb < b) pf += v;
        }
        total[t] = tot; pref[t] = pf;
    }
    __syncthreads();
    if (t == 0) {
        int tok = 0, tile = 0;
        for (int k = 0; k < 16; k++) {
            tokBase[k] = tok;
            tbase[k] = tile;
            int ntk = (total[k] + TILE - 1) / TILE;
            tok += ntk * TILE;
            tile += ntk;
        }
        tbase[16] = tile;
        if (b == 0) nT[0] = tile;
    }
    __syncthreads();
    if (b == 0) {
        for (int i = t; i < NT_MAX; i += 256) {
            int tk = 0;
            if (i < tbase[16]) {
#pragma unroll
                for (int k = 0; k < 16; k++) if (i >= tbase[k]) tk = k;
            }
            tileTask[i] = tk;
        }
    }
    int tk[8], my[8];
#pragma unroll
    for (int i = 0; i < 8; i++) {
        int idx = b * 2048 + i * 256 + t;
        tk[i] = task[idx];
        my[i] = atomicAdd(&rank[tk[i]], 1);
    }
#pragma unroll
    for (int i = 0; i < 8; i++) {
        int idx = b * 2048 + i * 256 + t;
        perm[tokBase[tk[i]] + pref[tk[i]] + my[i]] = idx;
    }
}

// ------------------------------------------------- fused MLP, fragment-major LDS
// Activations stored in exact MFMA-B-fragment order:
//   frag(tt,kt): elem addr = ((tt*(K/32)+kt)*64 + lane)*8 + j,
//   lane = (tok&15) + 16*((k&31)>>3), j = k&7.
// Reads are contiguous 1KB/wave ds_read_b128. Epilogue (C-layout: col=token,
// row=4 consecutive features) writes one b64 per acc tile.
// LDS: H1 16KB | XH2 16KB (X = first 8KB, H2 overlays after layer0) = 32.1KB
// -> 4 blocks/CU, 32 waves/CU.
__launch_bounds__(512, 8)
__global__ void mlp_kernel(const float* __restrict__ x_in,
                           const int* __restrict__ cmap,
                           const float* __restrict__ b0,
                           const float* __restrict__ b1,
                           const float* __restrict__ b2,
                           const ushort_t* __restrict__ W0p,
                           const ushort_t* __restrict__ W1p,
                           const ushort_t* __restrict__ W2p,
                           const int* __restrict__ tileTask,
                           const int* __restrict__ nTp,
                           const int* __restrict__ perm,
                           float* __restrict__ out) {
    __shared__ __align__(16) ushort_t H1[8192];    // 2 tt * 8 kt * 64 * 8 = 16 KB
    __shared__ __align__(16) ushort_t XH2[8192];   // X: frags [0,8) (8 KB); H2: frags [0,16)
    __shared__ int toks[TILE];

    int b = blockIdx.x;
    if (b >= nTp[0]) return;
    int t = threadIdx.x;
    int task = tileTask[b];
    int c0 = cmap[task], c1 = cmap[16 + task], c2 = cmap[32 + task];

    int w = t >> 6;                 // wave 0..7
    int lane = t & 63;
    int l15 = lane & 15, lq = lane >> 4;

    // ---- stage X: gather + cvt straight into B-fragment order (one b128/thread)
    {
        int r = t >> 4, q = t & 15;            // token r, covers k = q*8..q*8+7
        int tok = perm[b * TILE + r];
        if (q == 0) toks[r] = tok;
        float4 v0 = make_float4(0.f, 0.f, 0.f, 0.f), v1 = v0;
        if ((unsigned)tok < (unsigned)N_TOK) {
            const float4* src = reinterpret_cast<const float4*>(x_in) + (size_t)tok * 32 + q * 2;
            v0 = src[0]; v1 = src[1];
        }
        // frag coords: kt = q>>2, lane' = (r&15) + 16*(q&3), fragid = (r>>4)*4 + kt
        int fragid = (r >> 4) * 4 + (q >> 2);
        int lanep = (r & 15) + 16 * (q & 3);
        uint4 pk;
        pk.x = pk2(v0.x, v0.y); pk.y = pk2(v0.z, v0.w);
        pk.z = pk2(v1.x, v1.y); pk.w = pk2(v1.z, v1.w);
        *reinterpret_cast<uint4*>(&XH2[(fragid * 64 + lanep) << 3]) = pk;
    }
    __syncthreads();

    // ---- Layer 0: H1^T = W0^T X^T. Wave w: feature tiles {2w,2w+1} x 2 token tiles.
    {
        f4v acc[2][2];
#pragma unroll
        for (int mi = 0; mi < 2; mi++)
#pragma unroll
            for (int nt = 0; nt < 2; nt++) { f4v z = {0.f, 0.f, 0.f, 0.f}; acc[mi][nt] = z; }
        const ushort_t* Wc = W0p + (size_t)c0 * 32768;
#pragma unroll
        for (int kt = 0; kt < 4; kt++) {
            s8v wa[2];
#pragma unroll
            for (int mi = 0; mi < 2; mi++)
                wa[mi] = *reinterpret_cast<const s8v*>(Wc + ((((2 * w + mi) * 4 + kt) * 64 + lane) << 3));
            s8v xb[2];
#pragma unroll
            for (int nt = 0; nt < 2; nt++)
                xb[nt] = *reinterpret_cast<const s8v*>(&XH2[((nt * 4 + kt) * 64 + lane) << 3]);
#pragma unroll
            for (int mi = 0; mi < 2; mi++)
#pragma unroll
                for (int nt = 0; nt < 2; nt++)
                    acc[mi][nt] = __builtin_amdgcn_mfma_f32_16x16x32_bf16(wa[mi], xb[nt], acc[mi][nt], 0, 0, 0);
        }
#pragma unroll
        for (int mi = 0; mi < 2; mi++) {
            int ft = 2 * w + mi;
            float4 bv = *reinterpret_cast<const float4*>(b0 + c0 * 256 + ft * 16 + lq * 4);
            int kt_h = ft >> 1;
            int lanep = l15 + 16 * ((ft & 1) * 2 + (lq >> 1));
            int j0 = (lq & 1) * 4;
#pragma unroll
            for (int nt = 0; nt < 2; nt++) {
                float t0 = tanh_fast(acc[mi][nt][0] + bv.x);
                float t1 = tanh_fast(acc[mi][nt][1] + bv.y);
                float t2 = tanh_fast(acc[mi][nt][2] + bv.z);
                float t3 = tanh_fast(acc[mi][nt][3] + bv.w);
                uint2 pk; pk.x = pk2(t0, t1); pk.y = pk2(t2, t3);
                *reinterpret_cast<uint2*>(&H1[(((nt * 8 + kt_h) * 64 + lanep) << 3) + j0]) = pk;
            }
        }
    }
    __syncthreads();

    // ---- Layer 1: H2^T = W1^T H1^T. (H2 overlays X region.)
    {
        f4v acc[2][2];
#pragma unroll
        for (int mi = 0; mi < 2; mi++)
#pragma unroll
            for (int nt = 0; nt < 2; nt++) { f4v z = {0.f, 0.f, 0.f, 0.f}; acc[mi][nt] = z; }
        const ushort_t* Wc = W1p + (size_t)c1 * 65536;
#pragma unroll
        for (int kt = 0; kt < 8; kt++) {
            s8v wa[2];
#pragma unroll
            for (int mi = 0; mi < 2; mi++)
                wa[mi] = *reinterpret_cast<const s8v*>(Wc + ((((2 * w + mi) * 8 + kt) * 64 + lane) << 3));
            s8v xb[2];
#pragma unroll
            for (int nt = 0; nt < 2; nt++)
                xb[nt] = *reinterpret_cast<const s8v*>(&H1[((nt * 8 + kt) * 64 + lane) << 3]);
#pragma unroll
            for (int mi = 0; mi < 2; mi++)
#pragma unroll
                for (int nt = 0; nt < 2; nt++)
                    acc[mi][nt] = __builtin_amdgcn_mfma_f32_16x16x32_bf16(wa[mi], xb[nt], acc[mi][nt], 0, 0, 0);
        }
#pragma unroll
        for (int mi = 0; mi < 2; mi++) {
            int ft = 2 * w + mi;
            float4 bv = *reinterpret_cast<const float4*>(b1 + c1 * 256 + ft * 16 + lq * 4);
            int kt_h = ft >> 1;
            int lanep = l15 + 16 * ((ft & 1) * 2 + (lq >> 1));
            int j0 = (lq & 1) * 4;
#pragma unroll
            for (int nt = 0; nt < 2; nt++) {
                float t0 = tanh_fast(acc[mi][nt][0] + bv.x);
                float t1 = tanh_fast(acc[mi][nt][1] + bv.y);
                float t2 = tanh_fast(acc[mi][nt][2] + bv.z);
                float t3 = tanh_fast(acc[mi][nt][3] + bv.w);
                uint2 pk; pk.x = pk2(t0, t1); pk.y = pk2(t2, t3);
                *reinterpret_cast<uint2*>(&XH2[(((nt * 8 + kt_h) * 64 + lanep) << 3) + j0]) = pk;
            }
        }
    }
    __syncthreads();

    // ---- Layer 2: O^T = W2^T H2^T. 4 mt x 2 nt tiles / 8 waves = 1 tile/wave.
    {
        int mt = w & 3, nt = w >> 2;
        f4v acc = {0.f, 0.f, 0.f, 0.f};
        const ushort_t* Wc = W2p + (size_t)c2 * 16384;
#pragma unroll
        for (int kt = 0; kt < 8; kt++) {
            s8v wa = *reinterpret_cast<const s8v*>(Wc + (((mt * 8 + kt) * 64 + lane) << 3));
            s8v xb = *reinterpret_cast<const s8v*>(&XH2[((nt * 8 + kt) * 64 + lane) << 3]);
            acc = __builtin_amdgcn_mfma_f32_16x16x32_bf16(wa, xb, acc, 0, 0, 0);
        }
        int tok = toks[nt * 16 + l15];
        if ((unsigned)tok < (unsigned)N_TOK) {
            float4 bv = *reinterpret_cast<const float4*>(b2 + c2 * 64 + mt * 16 + lq * 4);
            float4 o;
            o.x = acc[0] + bv.x; o.y = acc[1] + bv.y;
            o.z = acc[2] + bv.z; o.w = acc[3] + bv.w;
            *reinterpret_cast<float4*>(out + (size_t)tok * 64 + mt * 16 + lq * 4) = o;
        }
    }
}

// ---------------------------------------------------------------- launch
extern "C" void kernel_launch(void* const* d_in, const int* in_sizes, int n_in,
                              void* d_out, int out_size, void* d_ws, size_t ws_size,
                              hipStream_t stream) {
    const float* inputs = (const float*)d_in[0];
    const int*   task   = (const int*)d_in[1];
    const int*   cmap   = (const int*)d_in[2];
    const float* W0     = (const float*)d_in[3];
    const float* b0     = (const float*)d_in[4];
    const float* W1     = (const float*)d_in[5];
    const float* b1     = (const float*)d_in[6];
    const float* W2     = (const float*)d_in[7];
    const float* b2     = (const float*)d_in[8];
    float* out = (float*)d_out;

    char* ws = (char*)d_ws;
    int* blockCounts = (int*)(ws + 0);            // 64*16*4 = 4096 B
    int* nT          = (int*)(ws + 4096);         // 4 B
    int* tileTask    = (int*)(ws + 4160);         // 4112*4 = 16448 B
    int* perm        = (int*)(ws + 20608);        // 4112*32*4 = 526336 B
    ushort_t* W0p    = (ushort_t*)(ws + 546944);  // 262144 B
    ushort_t* W1p    = (ushort_t*)(ws + 809088);  // 524288 B
    ushort_t* W2p    = (ushort_t*)(ws + 1333376); // 131072 B -> total ~1.40 MB

    prep_hist_kernel<<<288, 256, 0, stream>>>(W0, W1, W2, W0p, W1p, W2p, task, blockCounts);
    sort_kernel<<<64, 256, 0, stream>>>(task, blockCounts, tileTask, nT, perm);
    mlp_kernel<<<NT_MAX, 512, 0, stream>>>(inputs, cmap, b0, b1, b2,
                                           W0p, W1p, W2p, tileTask, nT, perm, out);
}